// Round 16
// baseline (102.471 us; speedup 1.0000x reference)
//
#include <hip/hip_runtime.h>
#include <hip/hip_bf16.h>

#define Bb 2
#define Ss 2048
#define Ee 1024
#define Hh 16
#define Dh 64
#define QSCALE 0.18033688011112042f  // log2(e) / sqrt(Dh)

using u16 = unsigned short;
using u32 = unsigned int;
typedef __attribute__((ext_vector_type(8))) short short8;
typedef __attribute__((ext_vector_type(8))) u16 ushort8;
typedef __attribute__((ext_vector_type(4))) float f32x4;
typedef __attribute__((ext_vector_type(16))) float f32x16;
typedef __attribute__((ext_vector_type(4))) u32 uint4v;

#define GAS __attribute__((address_space(1)))
#define LAS __attribute__((address_space(3)))

__device__ __forceinline__ void gload16(const u16* g, u16* l) {
  __builtin_amdgcn_global_load_lds((const GAS unsigned int*)g,
                                   (LAS unsigned int*)l, 16, 0, 0);
}

__device__ __forceinline__ u16 f2bf(float f) {
  union { float f; unsigned u; } v;
  v.f = f;
  unsigned u = v.u;
  unsigned r = (u + 0x7FFFu + ((u >> 16) & 1u)) >> 16;
  return (u16)r;
}

// ---------------- fp32 -> bf16 conversion (weights only; X fused into GEMM) ----------------
__global__ __launch_bounds__(256) void cvt_w(
    const float* __restrict__ wq, const float* __restrict__ wk,
    const float* __restrict__ wv, u16* __restrict__ wqo,
    u16* __restrict__ wko, u16* __restrict__ wvo) {
  const int b = blockIdx.x;            // 0..1535
  const int which = b >> 9;
  const float* s = which == 0 ? wq : (which == 1 ? wk : wv);
  u16* d = which == 0 ? wqo : (which == 1 ? wko : wvo);
  const int i = (b & 511) * 256 + threadIdx.x;
  const float* p = s + (size_t)i * 8;
  ushort8 o;
#pragma unroll
  for (int j = 0; j < 8; ++j) o[j] = f2bf(p[j]);
  *(ushort8*)(d + (size_t)i * 8) = o;
}

// ---------------- fused QKV GEMM: BM=128 x BN=384, X converted in-staging ----------------
// 512 threads / 8 waves (2M x 4N), BK=32 double-buffered, perfect-fill grid 256.
// A-tile staged from FP32 x directly: 2x float4 load -> f2bf (same RNE as the
// old cvt pass -> bit-identical) -> ds_write_b128 to the exact linear slot
// global_load_lds used. B staged via gload16 as before. Loop order (R13-proven):
// issue A-fp32(next), issue B-gload(next), compute(cur), cvt+ds_write A(next),
// barrier (drains vm+lgkm). Buffers disjoint -> race-free. k-ascending
// accumulation preserved -> bit-identical output vs R14.
__global__ __launch_bounds__(512, 2) void qkv_gemm(
    const float* __restrict__ Xf, const u16* __restrict__ Wcat,
    const float* __restrict__ bq, const float* __restrict__ bk,
    const float* __restrict__ bv,
    u16* __restrict__ Qo, u16* __restrict__ Ko, u16* __restrict__ Vo) {
  __shared__ u16 Ast[2][128][32];  // 16 KB, linear
  __shared__ u16 Bst[2][384][32];  // 48 KB, linear (global_load_lds dest)
  const int tid = threadIdx.x;
  const int lane = tid & 63;
  const int w = tid >> 6;          // 0..7
  const int wm = w >> 2, wn = w & 3;
  const int c = lane & 15, g = lane >> 4;
  const int flat = blockIdx.x;     // 256 blocks = 1/CU exactly
  const int m0 = (flat >> 3) * 128;
  const int n0 = (flat & 7) * 384;

  bool isv[6];
#pragma unroll
  for (int nf = 0; nf < 6; ++nf) isv[nf] = (n0 + wn * 96 + nf * 16) >= 2048;

  f32x4 acc[4][6] = {};

  // per-thread A-staging geometry (identical layout to the old gload16 path)
  const int elemA = tid * 8;                 // u16-elem index within 128x32 tile
  const int arow = elemA >> 5, acol = elemA & 31;
  const float* Arow = Xf + (size_t)(m0 + arow) * 1024 + acol;
  u16* AstSlot0 = &Ast[0][0][0] + elemA;     // == wave base w*512 + lane*8
  u16* AstSlot1 = &Ast[1][0][0] + elemA;

  // prologue: stage k-step 0 into buf 0
  {
    f32x4 a0 = *(const f32x4*)(Arow + 0);
    f32x4 a1 = *(const f32x4*)(Arow + 4);
    ushort8 o;
#pragma unroll
    for (int j = 0; j < 4; ++j) { o[j] = f2bf(a0[j]); o[4 + j] = f2bf(a1[j]); }
    *(ushort8*)AstSlot0 = o;
#pragma unroll
    for (int i = 0; i < 3; ++i) {
      const int elem = i * 4096 + tid * 8;
      gload16(Wcat + (size_t)(n0 + (elem >> 5)) * 1024 + (elem & 31),
              &Bst[0][0][0] + i * 4096 + w * 512);
    }
  }
  __syncthreads();

  for (int kt = 0; kt < 32; ++kt) {
    const int nxt = (kt + 1) & 1;
    f32x4 a0, a1;
    if (kt < 31) {
      const int k0n = (kt + 1) * 32;
      // (1a) issue next A fp32 loads first — land during compute below
      a0 = *(const f32x4*)(Arow + k0n + 0);
      a1 = *(const f32x4*)(Arow + k0n + 4);
      // (1b) issue next B staging
#pragma unroll
      for (int i = 0; i < 3; ++i) {
        const int elem = i * 4096 + tid * 8;
        gload16(Wcat + (size_t)(n0 + (elem >> 5)) * 1024 + k0n + (elem & 31),
                &Bst[nxt][0][0] + i * 4096 + w * 512);
      }
    }
    // (2) compute current k-step from buf[kt&1]
    const int cb = kt & 1;
    short8 af[4], bf[6];
#pragma unroll
    for (int mf = 0; mf < 4; ++mf)
      af[mf] = *(const short8*)&Ast[cb][wm * 64 + mf * 16 + c][g * 8];
#pragma unroll
    for (int nf = 0; nf < 6; ++nf)
      bf[nf] = *(const short8*)&Bst[cb][wn * 96 + nf * 16 + c][g * 8];
#pragma unroll
    for (int nf = 0; nf < 6; ++nf) {
      if (isv[nf]) {
#pragma unroll
        for (int mf = 0; mf < 4; ++mf)
          acc[mf][nf] = __builtin_amdgcn_mfma_f32_16x16x32_bf16(
              bf[nf], af[mf], acc[mf][nf], 0, 0, 0);
      } else {
#pragma unroll
        for (int mf = 0; mf < 4; ++mf)
          acc[mf][nf] = __builtin_amdgcn_mfma_f32_16x16x32_bf16(
              af[mf], bf[nf], acc[mf][nf], 0, 0, 0);
      }
    }
    // (3) convert + write next A tile (fp32 loads have had all of compute to land)
    if (kt < 31) {
      ushort8 o;
#pragma unroll
      for (int j = 0; j < 4; ++j) { o[j] = f2bf(a0[j]); o[4 + j] = f2bf(a1[j]); }
      *(ushort8*)(nxt ? AstSlot1 : AstSlot0) = o;
    }
    // (4) drain staged loads + LDS writes + readers-done fence, once per k-step
    __syncthreads();
  }

  // epilogue: per-frag normal (Q/K) or transposed (V) store
#pragma unroll
  for (int nf = 0; nf < 6; ++nf) {
    const int nc0 = n0 + wn * 96 + nf * 16;
    if (nc0 < 2048) {
      const int which = nc0 >> 10;  // 0 = Q, 1 = K
      u16* Oo = which == 0 ? Qo : Ko;
      const float* bias = which == 0 ? bq : bk;
      const float scl = which == 0 ? QSCALE : 1.0f;
      const int ncol = (nc0 & 1023) + c;
      const float bval = bias[ncol];
      const int hh = ncol >> 6, dd = ncol & 63;
#pragma unroll
      for (int mf = 0; mf < 4; ++mf) {
#pragma unroll
        for (int r = 0; r < 4; ++r) {
          const int m = m0 + wm * 64 + mf * 16 + g * 4 + r;
          const int bb = m >> 11, ss = m & 2047;
          Oo[(((size_t)bb * Hh + hh) * Ss + ss) * Dh + dd] =
              f2bf((acc[mf][nf][r] + bval) * scl);
        }
      }
    } else {
      // transposed frag: D row = n-local (g*4+r), col = m-local (c)
#pragma unroll
      for (int r = 0; r < 4; ++r) {
        const int ncol = (nc0 - 2048) + g * 4 + r;
        const float bval = bv[ncol];
        const int hh = ncol >> 6, dd = ncol & 63;
#pragma unroll
        for (int mf = 0; mf < 4; ++mf) {
          const int m = m0 + wm * 64 + mf * 16 + c;
          const int bb = m >> 11, ss = m & 2047;
          Vo[(((size_t)bb * Hh + hh) * Dh + dd) * Ss + ss] =
              f2bf(acc[mf][nf][r] + bval);
        }
      }
    }
  }
}

// ---------------- flash attention: 32x32 swapped-QK^T, sub-level pipelined ----------------
// (unchanged from R10 — known-good)
__global__ __launch_bounds__(256, 2) void attn(
    const u16* __restrict__ Q, const u16* __restrict__ K,
    const u16* __restrict__ VT, float* __restrict__ out) {
  __shared__ u16 Kst[2][2][64][64];  // [buf][sub][key][d] (content XOR-swizzled)
  __shared__ u16 Vst[2][2][64][64];  // [buf][sub][d][key] (content XOR-swizzled)
  const int tid = threadIdx.x;
  const int lane = tid & 63;
  const int w = tid >> 6;
  const int c5 = lane & 31, g2 = lane >> 5;
  const int flat = blockIdx.x;
  const int bh = (flat & 7) * 4 + ((flat >> 3) >> 4);
  const int q0 = ((flat >> 3) & 15) * 128;
  const u16* Qb = Q + (size_t)bh * Ss * Dh;
  const u16* Kb = K + (size_t)bh * Ss * Dh;
  const u16* VTb = VT + (size_t)bh * Ss * Dh;  // [Dh][Ss]

  const int srow = lane >> 3;                       // 0..7
  const int scolx = ((lane & 7) * 8) ^ (srow * 8);  // swizzled src col (u16)

  const u16* Qrow = Qb + (size_t)(q0 + w * 32 + c5) * Dh + 8 * g2;
  short8 qf[4];
#pragma unroll
  for (int s = 0; s < 4; ++s) qf[s] = *(const short8*)(Qrow + 16 * s);

  short8 ones;
#pragma unroll
  for (int j = 0; j < 8; ++j) ones[j] = (short)0x3F80;
  f32x16 ZZ = {};  // persistent zero C-operand

  const int cxor = (c5 & 7) << 4;
  int slot[4];
#pragma unroll
  for (int s = 0; s < 4; ++s) slot[s] = c5 * 128 + ((32 * s + 16 * g2) ^ cxor);

  // prologue: stage tile 0 (both subs) into buf 0
#pragma unroll
  for (int sub = 0; sub < 2; ++sub) {
#pragma unroll
    for (int p = 0; p < 2; ++p) {
      const int row = w * 8 + srow + p * 32;
      gload16(Kb + (size_t)(sub * 64 + row) * Dh + scolx,
              &Kst[0][sub][0][0] + w * 512 + p * 2048);
      gload16(VTb + (size_t)row * Ss + sub * 64 + scolx,
              &Vst[0][sub][0][0] + w * 512 + p * 2048);
    }
  }

  f32x16 oacc0 = {}, oacc1 = {}, lacc = {};

  for (int kt = 0; kt < 16; ++kt) {
    __syncthreads();  // drains vmcnt -> tile kt staged; prev reads done
    if (kt < 15) {
      const int k0n = (kt + 1) * 128;
      const int nb = (kt + 1) & 1;
#pragma unroll
      for (int sub = 0; sub < 2; ++sub) {
#pragma unroll
        for (int p = 0; p < 2; ++p) {
          const int row = w * 8 + srow + p * 32;
          gload16(Kb + (size_t)(k0n + sub * 64 + row) * Dh + scolx,
                  &Kst[nb][sub][0][0] + w * 512 + p * 2048);
          gload16(VTb + (size_t)row * Ss + k0n + sub * 64 + scolx,
                  &Vst[nb][sub][0][0] + w * 512 + p * 2048);
        }
      }
    }
    const char* kb0 = (const char*)&Kst[kt & 1][0][0][0];
    const char* kb1 = (const char*)&Kst[kt & 1][1][0][0];
    const char* vb0 = (const char*)&Vst[kt & 1][0][0][0];
    const char* vb1 = (const char*)&Vst[kt & 1][1][0][0];

    // ---- QK^T for BOTH subs (swapped: sc = K-block * Q -> D[key][q]) ----
    f32x16 sA0, sA1, sB0, sB1;
    __builtin_amdgcn_s_setprio(1);
    {
      short8 ka0 = *(const short8*)(kb0 + slot[0]);
      short8 ka1 = *(const short8*)(kb0 + slot[0] + 4096);
      short8 kc0 = *(const short8*)(kb1 + slot[0]);
      short8 kc1 = *(const short8*)(kb1 + slot[0] + 4096);
      sA0 = __builtin_amdgcn_mfma_f32_32x32x16_bf16(ka0, qf[0], ZZ, 0, 0, 0);
      sA1 = __builtin_amdgcn_mfma_f32_32x32x16_bf16(ka1, qf[0], ZZ, 0, 0, 0);
      sB0 = __builtin_amdgcn_mfma_f32_32x32x16_bf16(kc0, qf[0], ZZ, 0, 0, 0);
      sB1 = __builtin_amdgcn_mfma_f32_32x32x16_bf16(kc1, qf[0], ZZ, 0, 0, 0);
    }
#pragma unroll
    for (int s = 1; s < 4; ++s) {
      short8 ka0 = *(const short8*)(kb0 + slot[s]);
      short8 ka1 = *(const short8*)(kb0 + slot[s] + 4096);
      short8 kc0 = *(const short8*)(kb1 + slot[s]);
      short8 kc1 = *(const short8*)(kb1 + slot[s] + 4096);
      sA0 = __builtin_amdgcn_mfma_f32_32x32x16_bf16(ka0, qf[s], sA0, 0, 0, 0);
      sA1 = __builtin_amdgcn_mfma_f32_32x32x16_bf16(ka1, qf[s], sA1, 0, 0, 0);
      sB0 = __builtin_amdgcn_mfma_f32_32x32x16_bf16(kc0, qf[s], sB0, 0, 0, 0);
      sB1 = __builtin_amdgcn_mfma_f32_32x32x16_bf16(kc1, qf[s], sB1, 0, 0, 0);
    }
    __builtin_amdgcn_s_setprio(0);

    // ---- exp/pack sub0 ----
    u32 pkvA[2][8];
#pragma unroll
    for (int i = 0; i < 8; ++i) {
      const u32 e0 = __builtin_bit_cast(u32, __builtin_amdgcn_exp2f(sA0[2 * i]));
      const u32 e1 = __builtin_bit_cast(u32, __builtin_amdgcn_exp2f(sA0[2 * i + 1]));
      pkvA[0][i] = __builtin_amdgcn_perm(e1, e0, 0x07060302u);
    }
#pragma unroll
    for (int i = 0; i < 8; ++i) {
      const u32 e0 = __builtin_bit_cast(u32, __builtin_amdgcn_exp2f(sA1[2 * i]));
      const u32 e1 = __builtin_bit_cast(u32, __builtin_amdgcn_exp2f(sA1[2 * i + 1]));
      pkvA[1][i] = __builtin_amdgcn_perm(e1, e0, 0x07060302u);
    }

    // ---- PV sub0 (overlaps with exp sub1 below) ----
    __builtin_amdgcn_s_setprio(1);
#pragma unroll
    for (int sp = 0; sp < 4; ++sp) {
      const int kb = sp >> 1, sg = sp & 1;
      u32 x0 = pkvA[kb][4 * sg + 0], y0 = pkvA[kb][4 * sg + 2];
      u32 x1 = pkvA[kb][4 * sg + 1], y1 = pkvA[kb][4 * sg + 3];
      asm("v_permlane32_swap_b32 %0, %1" : "+v"(x0), "+v"(y0));
      asm("v_permlane32_swap_b32 %0, %1" : "+v"(x1), "+v"(y1));
      uint4v av;
      av[0] = x0; av[1] = x1; av[2] = y0; av[3] = y1;
      const short8 af = __builtin_bit_cast(short8, av);
      short8 vf0 = *(const short8*)(vb0 + slot[sp]);
      short8 vf1 = *(const short8*)(vb0 + slot[sp] + 4096);
      lacc = __builtin_amdgcn_mfma_f32_32x32x16_bf16(af, ones, lacc, 0, 0, 0);
      oacc0 = __builtin_amdgcn_mfma_f32_32x32x16_bf16(af, vf0, oacc0, 0, 0, 0);
      oacc1 = __builtin_amdgcn_mfma_f32_32x32x16_bf16(af, vf1, oacc1, 0, 0, 0);
    }
    __builtin_amdgcn_s_setprio(0);

    // ---- exp/pack sub1 ----
    u32 pkvB[2][8];
#pragma unroll
    for (int i = 0; i < 8; ++i) {
      const u32 e0 = __builtin_bit_cast(u32, __builtin_amdgcn_exp2f(sB0[2 * i]));
      const u32 e1 = __builtin_bit_cast(u32, __builtin_amdgcn_exp2f(sB0[2 * i + 1]));
      pkvB[0][i] = __builtin_amdgcn_perm(e1, e0, 0x07060302u);
    }
#pragma unroll
    for (int i = 0; i < 8; ++i) {
      const u32 e0 = __builtin_bit_cast(u32, __builtin_amdgcn_exp2f(sB1[2 * i]));
      const u32 e1 = __builtin_bit_cast(u32, __builtin_amdgcn_exp2f(sB1[2 * i + 1]));
      pkvB[1][i] = __builtin_amdgcn_perm(e1, e0, 0x07060302u);
    }

    // ---- PV sub1 ----
    __builtin_amdgcn_s_setprio(1);
#pragma unroll
    for (int sp = 0; sp < 4; ++sp) {
      const int kb = sp >> 1, sg = sp & 1;
      u32 x0 = pkvB[kb][4 * sg + 0], y0 = pkvB[kb][4 * sg + 2];
      u32 x1 = pkvB[kb][4 * sg + 1], y1 = pkvB[kb][4 * sg + 3];
      asm("v_permlane32_swap_b32 %0, %1" : "+v"(x0), "+v"(y0));
      asm("v_permlane32_swap_b32 %0, %1" : "+v"(x1), "+v"(y1));
      uint4v av;
      av[0] = x0; av[1] = x1; av[2] = y0; av[3] = y1;
      const short8 af = __builtin_bit_cast(short8, av);
      short8 vf0 = *(const short8*)(vb1 + slot[sp]);
      short8 vf1 = *(const short8*)(vb1 + slot[sp] + 4096);
      lacc = __builtin_amdgcn_mfma_f32_32x32x16_bf16(af, ones, lacc, 0, 0, 0);
      oacc0 = __builtin_amdgcn_mfma_f32_32x32x16_bf16(af, vf0, oacc0, 0, 0, 0);
      oacc1 = __builtin_amdgcn_mfma_f32_32x32x16_bf16(af, vf1, oacc1, 0, 0, 0);
    }
    __builtin_amdgcn_s_setprio(0);
  }

  // ---- epilogue ----
  float* ob = out + (size_t)bh * Ss * Dh;
#pragma unroll
  for (int r = 0; r < 16; ++r) {
    const float inv = 1.0f / lacc[r];
    const int q = q0 + w * 32 + (r & 3) + 8 * (r >> 2) + 4 * g2;
    ob[(size_t)q * Dh + c5] = oacc0[r] * inv;
    ob[(size_t)q * Dh + 32 + c5] = oacc1[r] * inv;
  }
}

// ---------------- launch ----------------
extern "C" void kernel_launch(void* const* d_in, const int* in_sizes, int n_in,
                              void* d_out, int out_size, void* d_ws, size_t ws_size,
                              hipStream_t stream) {
  const float* x = (const float*)d_in[0];
  const float* Wq = (const float*)d_in[1];
  const float* bq = (const float*)d_in[2];
  const float* Wk = (const float*)d_in[3];
  const float* bk = (const float*)d_in[4];
  const float* Wv = (const float*)d_in[5];
  const float* bv = (const float*)d_in[6];
  float* out = (float*)d_out;

  if (ws_size < (size_t)(38u << 20)) return;  // need 38 MiB scratch
  char* ws = (char*)d_ws;
  u16* Qb = (u16*)(ws + (size_t)(0u << 20));
  u16* Kb = (u16*)(ws + (size_t)(8u << 20));
  u16* Vb = (u16*)(ws + (size_t)(16u << 20));   // transposed [B,H,Dh,S]
  u16* Wqb = (u16*)(ws + (size_t)(32u << 20));  // Wq|Wk|Wv contiguous (6 MiB)
  u16* Wkb = (u16*)(ws + (size_t)(34u << 20));
  u16* Wvb = (u16*)(ws + (size_t)(36u << 20));

  cvt_w<<<1536, 256, 0, stream>>>(Wq, Wk, Wv, Wqb, Wkb, Wvb);
  qkv_gemm<<<256, 512, 0, stream>>>(x, Wqb, bq, bk, bv, Qb, Kb, Vb);
  attn<<<512, 256, 0, stream>>>(Qb, Kb, Vb, out);
}

// Round 17
// 99.018 us; speedup vs baseline: 1.0349x; 1.0349x over previous
//
#include <hip/hip_runtime.h>
#include <hip/hip_bf16.h>

#define Bb 2
#define Ss 2048
#define Ee 1024
#define Hh 16
#define Dh 64
#define QSCALE 0.18033688011112042f  // log2(e) / sqrt(Dh)

using u16 = unsigned short;
using u32 = unsigned int;
typedef __attribute__((ext_vector_type(8))) short short8;
typedef __attribute__((ext_vector_type(8))) u16 ushort8;
typedef __attribute__((ext_vector_type(4))) float f32x4;
typedef __attribute__((ext_vector_type(16))) float f32x16;
typedef __attribute__((ext_vector_type(4))) u32 uint4v;

#define GAS __attribute__((address_space(1)))
#define LAS __attribute__((address_space(3)))

__device__ __forceinline__ void gload16(const u16* g, u16* l) {
  __builtin_amdgcn_global_load_lds((const GAS unsigned int*)g,
                                   (LAS unsigned int*)l, 16, 0, 0);
}

__device__ __forceinline__ u16 f2bf(float f) {
  union { float f; unsigned u; } v;
  v.f = f;
  unsigned u = v.u;
  unsigned r = (u + 0x7FFFu + ((u >> 16) & 1u)) >> 16;
  return (u16)r;
}

// ---------------- fp32 -> bf16 conversion (x + 3 weights, one launch) ----------------
__global__ __launch_bounds__(256) void cvt_all(
    const float* __restrict__ x, const float* __restrict__ wq,
    const float* __restrict__ wk, const float* __restrict__ wv,
    u16* __restrict__ xo, u16* __restrict__ wqo, u16* __restrict__ wko,
    u16* __restrict__ wvo) {
  const int b = blockIdx.x;
  const float* s;
  u16* d;
  int i;
  if (b < 2048) {
    s = x; d = xo; i = b * 256 + threadIdx.x;
  } else {
    const int wb = b - 2048;
    const int which = wb >> 9;
    s = which == 0 ? wq : (which == 1 ? wk : wv);
    d = which == 0 ? wqo : (which == 1 ? wko : wvo);
    i = (wb & 511) * 256 + threadIdx.x;
  }
  const float* p = s + (size_t)i * 8;
  ushort8 o;
#pragma unroll
  for (int j = 0; j < 8; ++j) o[j] = f2bf(p[j]);
  *(ushort8*)(d + (size_t)i * 8) = o;
}

// ---------------- fused QKV GEMM: BM=128 x BN=384, perfect-fill grid 256 ----------------
// (R14/R15 best-known: bf16 Xb staging via global_load_lds, BK=32 dbuf,
// issue-first/compute/barrier order, per-frag V operand swap.)
__global__ __launch_bounds__(512, 2) void qkv_gemm(
    const u16* __restrict__ Xb, const u16* __restrict__ Wcat,
    const float* __restrict__ bq, const float* __restrict__ bk,
    const float* __restrict__ bv,
    u16* __restrict__ Qo, u16* __restrict__ Ko, u16* __restrict__ Vo) {
  __shared__ u16 Ast[2][128][32];  // 16 KB, linear (global_load_lds dest)
  __shared__ u16 Bst[2][384][32];  // 48 KB
  const int tid = threadIdx.x;
  const int lane = tid & 63;
  const int w = tid >> 6;          // 0..7
  const int wm = w >> 2, wn = w & 3;
  const int c = lane & 15, g = lane >> 4;
  const int flat = blockIdx.x;     // 256 blocks = 1/CU exactly
  const int m0 = (flat >> 3) * 128;
  const int n0 = (flat & 7) * 384;

  bool isv[6];
#pragma unroll
  for (int nf = 0; nf < 6; ++nf) isv[nf] = (n0 + wn * 96 + nf * 16) >= 2048;

  f32x4 acc[4][6] = {};

  // prologue: stage k-step 0 into buf 0
  {
    const int elemA = tid * 8;
    gload16(Xb + (size_t)(m0 + (elemA >> 5)) * 1024 + (elemA & 31),
            &Ast[0][0][0] + w * 512);
#pragma unroll
    for (int i = 0; i < 3; ++i) {
      const int elem = i * 4096 + tid * 8;
      gload16(Wcat + (size_t)(n0 + (elem >> 5)) * 1024 + (elem & 31),
              &Bst[0][0][0] + i * 4096 + w * 512);
    }
  }
  __syncthreads();

  for (int kt = 0; kt < 32; ++kt) {
    // (1) issue next k-step's staging first — flies during compute below
    if (kt < 31) {
      const int k0n = (kt + 1) * 32;
      const int nb = (kt + 1) & 1;
      const int elemA = tid * 8;
      gload16(Xb + (size_t)(m0 + (elemA >> 5)) * 1024 + k0n + (elemA & 31),
              &Ast[nb][0][0] + w * 512);
#pragma unroll
      for (int i = 0; i < 3; ++i) {
        const int elem = i * 4096 + tid * 8;
        gload16(Wcat + (size_t)(n0 + (elem >> 5)) * 1024 + k0n + (elem & 31),
                &Bst[nb][0][0] + i * 4096 + w * 512);
      }
    }
    // (2) compute current k-step from buf[kt&1]
    const int cb = kt & 1;
    short8 af[4], bf[6];
#pragma unroll
    for (int mf = 0; mf < 4; ++mf)
      af[mf] = *(const short8*)&Ast[cb][wm * 64 + mf * 16 + c][g * 8];
#pragma unroll
    for (int nf = 0; nf < 6; ++nf)
      bf[nf] = *(const short8*)&Bst[cb][wn * 96 + nf * 16 + c][g * 8];
#pragma unroll
    for (int nf = 0; nf < 6; ++nf) {
      if (isv[nf]) {
#pragma unroll
        for (int mf = 0; mf < 4; ++mf)
          acc[mf][nf] = __builtin_amdgcn_mfma_f32_16x16x32_bf16(
              bf[nf], af[mf], acc[mf][nf], 0, 0, 0);
      } else {
#pragma unroll
        for (int mf = 0; mf < 4; ++mf)
          acc[mf][nf] = __builtin_amdgcn_mfma_f32_16x16x32_bf16(
              af[mf], bf[nf], acc[mf][nf], 0, 0, 0);
      }
    }
    // (3) drain staged loads + readers-done fence, once per k-step
    __syncthreads();
  }

  // epilogue: per-frag normal (Q/K) or transposed (V) store
#pragma unroll
  for (int nf = 0; nf < 6; ++nf) {
    const int nc0 = n0 + wn * 96 + nf * 16;
    if (nc0 < 2048) {
      const int which = nc0 >> 10;  // 0 = Q, 1 = K
      u16* Oo = which == 0 ? Qo : Ko;
      const float* bias = which == 0 ? bq : bk;
      const float scl = which == 0 ? QSCALE : 1.0f;
      const int ncol = (nc0 & 1023) + c;
      const float bval = bias[ncol];
      const int hh = ncol >> 6, dd = ncol & 63;
#pragma unroll
      for (int mf = 0; mf < 4; ++mf) {
#pragma unroll
        for (int r = 0; r < 4; ++r) {
          const int m = m0 + wm * 64 + mf * 16 + g * 4 + r;
          const int bb = m >> 11, ss = m & 2047;
          Oo[(((size_t)bb * Hh + hh) * Ss + ss) * Dh + dd] =
              f2bf((acc[mf][nf][r] + bval) * scl);
        }
      }
    } else {
      // transposed frag: D row = n-local (g*4+r), col = m-local (c)
#pragma unroll
      for (int r = 0; r < 4; ++r) {
        const int ncol = (nc0 - 2048) + g * 4 + r;
        const float bval = bv[ncol];
        const int hh = ncol >> 6, dd = ncol & 63;
#pragma unroll
        for (int mf = 0; mf < 4; ++mf) {
          const int m = m0 + wm * 64 + mf * 16 + c;
          const int bb = m >> 11, ss = m & 2047;
          Vo[(((size_t)bb * Hh + hh) * Dh + dd) * Ss + ss] =
              f2bf(acc[mf][nf][r] + bval);
        }
      }
    }
  }
}

// ---------------- flash attention: 32x32 swapped-QK^T, sub-level pipelined ----------------
// (unchanged from R10 — known-good)
__global__ __launch_bounds__(256, 2) void attn(
    const u16* __restrict__ Q, const u16* __restrict__ K,
    const u16* __restrict__ VT, float* __restrict__ out) {
  __shared__ u16 Kst[2][2][64][64];  // [buf][sub][key][d] (content XOR-swizzled)
  __shared__ u16 Vst[2][2][64][64];  // [buf][sub][d][key] (content XOR-swizzled)
  const int tid = threadIdx.x;
  const int lane = tid & 63;
  const int w = tid >> 6;
  const int c5 = lane & 31, g2 = lane >> 5;
  const int flat = blockIdx.x;
  const int bh = (flat & 7) * 4 + ((flat >> 3) >> 4);
  const int q0 = ((flat >> 3) & 15) * 128;
  const u16* Qb = Q + (size_t)bh * Ss * Dh;
  const u16* Kb = K + (size_t)bh * Ss * Dh;
  const u16* VTb = VT + (size_t)bh * Ss * Dh;  // [Dh][Ss]

  const int srow = lane >> 3;                       // 0..7
  const int scolx = ((lane & 7) * 8) ^ (srow * 8);  // swizzled src col (u16)

  const u16* Qrow = Qb + (size_t)(q0 + w * 32 + c5) * Dh + 8 * g2;
  short8 qf[4];
#pragma unroll
  for (int s = 0; s < 4; ++s) qf[s] = *(const short8*)(Qrow + 16 * s);

  short8 ones;
#pragma unroll
  for (int j = 0; j < 8; ++j) ones[j] = (short)0x3F80;
  f32x16 ZZ = {};  // persistent zero C-operand

  const int cxor = (c5 & 7) << 4;
  int slot[4];
#pragma unroll
  for (int s = 0; s < 4; ++s) slot[s] = c5 * 128 + ((32 * s + 16 * g2) ^ cxor);

  // prologue: stage tile 0 (both subs) into buf 0
#pragma unroll
  for (int sub = 0; sub < 2; ++sub) {
#pragma unroll
    for (int p = 0; p < 2; ++p) {
      const int row = w * 8 + srow + p * 32;
      gload16(Kb + (size_t)(sub * 64 + row) * Dh + scolx,
              &Kst[0][sub][0][0] + w * 512 + p * 2048);
      gload16(VTb + (size_t)row * Ss + sub * 64 + scolx,
              &Vst[0][sub][0][0] + w * 512 + p * 2048);
    }
  }

  f32x16 oacc0 = {}, oacc1 = {}, lacc = {};

  for (int kt = 0; kt < 16; ++kt) {
    __syncthreads();  // drains vmcnt -> tile kt staged; prev reads done
    if (kt < 15) {
      const int k0n = (kt + 1) * 128;
      const int nb = (kt + 1) & 1;
#pragma unroll
      for (int sub = 0; sub < 2; ++sub) {
#pragma unroll
        for (int p = 0; p < 2; ++p) {
          const int row = w * 8 + srow + p * 32;
          gload16(Kb + (size_t)(k0n + sub * 64 + row) * Dh + scolx,
                  &Kst[nb][sub][0][0] + w * 512 + p * 2048);
          gload16(VTb + (size_t)row * Ss + k0n + sub * 64 + scolx,
                  &Vst[nb][sub][0][0] + w * 512 + p * 2048);
        }
      }
    }
    const char* kb0 = (const char*)&Kst[kt & 1][0][0][0];
    const char* kb1 = (const char*)&Kst[kt & 1][1][0][0];
    const char* vb0 = (const char*)&Vst[kt & 1][0][0][0];
    const char* vb1 = (const char*)&Vst[kt & 1][1][0][0];

    // ---- QK^T for BOTH subs (swapped: sc = K-block * Q -> D[key][q]) ----
    f32x16 sA0, sA1, sB0, sB1;
    __builtin_amdgcn_s_setprio(1);
    {
      short8 ka0 = *(const short8*)(kb0 + slot[0]);
      short8 ka1 = *(const short8*)(kb0 + slot[0] + 4096);
      short8 kc0 = *(const short8*)(kb1 + slot[0]);
      short8 kc1 = *(const short8*)(kb1 + slot[0] + 4096);
      sA0 = __builtin_amdgcn_mfma_f32_32x32x16_bf16(ka0, qf[0], ZZ, 0, 0, 0);
      sA1 = __builtin_amdgcn_mfma_f32_32x32x16_bf16(ka1, qf[0], ZZ, 0, 0, 0);
      sB0 = __builtin_amdgcn_mfma_f32_32x32x16_bf16(kc0, qf[0], ZZ, 0, 0, 0);
      sB1 = __builtin_amdgcn_mfma_f32_32x32x16_bf16(kc1, qf[0], ZZ, 0, 0, 0);
    }
#pragma unroll
    for (int s = 1; s < 4; ++s) {
      short8 ka0 = *(const short8*)(kb0 + slot[s]);
      short8 ka1 = *(const short8*)(kb0 + slot[s] + 4096);
      short8 kc0 = *(const short8*)(kb1 + slot[s]);
      short8 kc1 = *(const short8*)(kb1 + slot[s] + 4096);
      sA0 = __builtin_amdgcn_mfma_f32_32x32x16_bf16(ka0, qf[s], sA0, 0, 0, 0);
      sA1 = __builtin_amdgcn_mfma_f32_32x32x16_bf16(ka1, qf[s], sA1, 0, 0, 0);
      sB0 = __builtin_amdgcn_mfma_f32_32x32x16_bf16(kc0, qf[s], sB0, 0, 0, 0);
      sB1 = __builtin_amdgcn_mfma_f32_32x32x16_bf16(kc1, qf[s], sB1, 0, 0, 0);
    }
    __builtin_amdgcn_s_setprio(0);

    // ---- exp/pack sub0 ----
    u32 pkvA[2][8];
#pragma unroll
    for (int i = 0; i < 8; ++i) {
      const u32 e0 = __builtin_bit_cast(u32, __builtin_amdgcn_exp2f(sA0[2 * i]));
      const u32 e1 = __builtin_bit_cast(u32, __builtin_amdgcn_exp2f(sA0[2 * i + 1]));
      pkvA[0][i] = __builtin_amdgcn_perm(e1, e0, 0x07060302u);
    }
#pragma unroll
    for (int i = 0; i < 8; ++i) {
      const u32 e0 = __builtin_bit_cast(u32, __builtin_amdgcn_exp2f(sA1[2 * i]));
      const u32 e1 = __builtin_bit_cast(u32, __builtin_amdgcn_exp2f(sA1[2 * i + 1]));
      pkvA[1][i] = __builtin_amdgcn_perm(e1, e0, 0x07060302u);
    }

    // ---- PV sub0 (overlaps with exp sub1 below) ----
    __builtin_amdgcn_s_setprio(1);
#pragma unroll
    for (int sp = 0; sp < 4; ++sp) {
      const int kb = sp >> 1, sg = sp & 1;
      u32 x0 = pkvA[kb][4 * sg + 0], y0 = pkvA[kb][4 * sg + 2];
      u32 x1 = pkvA[kb][4 * sg + 1], y1 = pkvA[kb][4 * sg + 3];
      asm("v_permlane32_swap_b32 %0, %1" : "+v"(x0), "+v"(y0));
      asm("v_permlane32_swap_b32 %0, %1" : "+v"(x1), "+v"(y1));
      uint4v av;
      av[0] = x0; av[1] = x1; av[2] = y0; av[3] = y1;
      const short8 af = __builtin_bit_cast(short8, av);
      short8 vf0 = *(const short8*)(vb0 + slot[sp]);
      short8 vf1 = *(const short8*)(vb0 + slot[sp] + 4096);
      lacc = __builtin_amdgcn_mfma_f32_32x32x16_bf16(af, ones, lacc, 0, 0, 0);
      oacc0 = __builtin_amdgcn_mfma_f32_32x32x16_bf16(af, vf0, oacc0, 0, 0, 0);
      oacc1 = __builtin_amdgcn_mfma_f32_32x32x16_bf16(af, vf1, oacc1, 0, 0, 0);
    }
    __builtin_amdgcn_s_setprio(0);

    // ---- exp/pack sub1 ----
    u32 pkvB[2][8];
#pragma unroll
    for (int i = 0; i < 8; ++i) {
      const u32 e0 = __builtin_bit_cast(u32, __builtin_amdgcn_exp2f(sB0[2 * i]));
      const u32 e1 = __builtin_bit_cast(u32, __builtin_amdgcn_exp2f(sB0[2 * i + 1]));
      pkvB[0][i] = __builtin_amdgcn_perm(e1, e0, 0x07060302u);
    }
#pragma unroll
    for (int i = 0; i < 8; ++i) {
      const u32 e0 = __builtin_bit_cast(u32, __builtin_amdgcn_exp2f(sB1[2 * i]));
      const u32 e1 = __builtin_bit_cast(u32, __builtin_amdgcn_exp2f(sB1[2 * i + 1]));
      pkvB[1][i] = __builtin_amdgcn_perm(e1, e0, 0x07060302u);
    }

    // ---- PV sub1 ----
    __builtin_amdgcn_s_setprio(1);
#pragma unroll
    for (int sp = 0; sp < 4; ++sp) {
      const int kb = sp >> 1, sg = sp & 1;
      u32 x0 = pkvB[kb][4 * sg + 0], y0 = pkvB[kb][4 * sg + 2];
      u32 x1 = pkvB[kb][4 * sg + 1], y1 = pkvB[kb][4 * sg + 3];
      asm("v_permlane32_swap_b32 %0, %1" : "+v"(x0), "+v"(y0));
      asm("v_permlane32_swap_b32 %0, %1" : "+v"(x1), "+v"(y1));
      uint4v av;
      av[0] = x0; av[1] = x1; av[2] = y0; av[3] = y1;
      const short8 af = __builtin_bit_cast(short8, av);
      short8 vf0 = *(const short8*)(vb1 + slot[sp]);
      short8 vf1 = *(const short8*)(vb1 + slot[sp] + 4096);
      lacc = __builtin_amdgcn_mfma_f32_32x32x16_bf16(af, ones, lacc, 0, 0, 0);
      oacc0 = __builtin_amdgcn_mfma_f32_32x32x16_bf16(af, vf0, oacc0, 0, 0, 0);
      oacc1 = __builtin_amdgcn_mfma_f32_32x32x16_bf16(af, vf1, oacc1, 0, 0, 0);
    }
    __builtin_amdgcn_s_setprio(0);
  }

  // ---- epilogue ----
  float* ob = out + (size_t)bh * Ss * Dh;
#pragma unroll
  for (int r = 0; r < 16; ++r) {
    const float inv = 1.0f / lacc[r];
    const int q = q0 + w * 32 + (r & 3) + 8 * (r >> 2) + 4 * g2;
    ob[(size_t)q * Dh + c5] = oacc0[r] * inv;
    ob[(size_t)q * Dh + 32 + c5] = oacc1[r] * inv;
  }
}

// ---------------- launch ----------------
extern "C" void kernel_launch(void* const* d_in, const int* in_sizes, int n_in,
                              void* d_out, int out_size, void* d_ws, size_t ws_size,
                              hipStream_t stream) {
  const float* x = (const float*)d_in[0];
  const float* Wq = (const float*)d_in[1];
  const float* bq = (const float*)d_in[2];
  const float* Wk = (const float*)d_in[3];
  const float* bk = (const float*)d_in[4];
  const float* Wv = (const float*)d_in[5];
  const float* bv = (const float*)d_in[6];
  float* out = (float*)d_out;

  if (ws_size < (size_t)(38u << 20)) return;  // need 38 MiB scratch
  char* ws = (char*)d_ws;
  u16* Qb = (u16*)(ws + (size_t)(0u << 20));
  u16* Kb = (u16*)(ws + (size_t)(8u << 20));
  u16* Vb = (u16*)(ws + (size_t)(16u << 20));   // transposed [B,H,Dh,S]
  u16* Xb = (u16*)(ws + (size_t)(24u << 20));
  u16* Wqb = (u16*)(ws + (size_t)(32u << 20));  // Wq|Wk|Wv contiguous (6 MiB)
  u16* Wkb = (u16*)(ws + (size_t)(34u << 20));
  u16* Wvb = (u16*)(ws + (size_t)(36u << 20));

  cvt_all<<<3584, 256, 0, stream>>>(x, Wq, Wk, Wv, Xb, Wqb, Wkb, Wvb);
  qkv_gemm<<<256, 512, 0, stream>>>(Xb, Wqb, bq, bk, bv, Qb, Kb, Vb);
  attn<<<512, 256, 0, stream>>>(Qb, Kb, Vb, out);
}